// Round 1
// baseline (1044.016 us; speedup 1.0000x reference)
//
#include <hip/hip_runtime.h>
#include <hip/hip_bf16.h>

typedef unsigned short u16;
typedef unsigned int u32;
typedef short short8 __attribute__((ext_vector_type(8)));
typedef u16 u16x8 __attribute__((ext_vector_type(8)));
typedef float f32x16 __attribute__((ext_vector_type(16)));

#define HD 2880          // H == I == 2880
#define GUN 5760         // 2*I
#define NEXP 8
#define NTOK 1024
#define NASSIGN 4096     // T*K
#define MAXPAD 5120      // 4096 + 8*127 rounded up
#define MAXTILES 40      // sum ceil(cnt_e/128) <= 39
#define SROWS 90         // 2880/32

// ---------------- exact mxfp4 quant helpers ----------------
// Replicates LEVELS[searchsorted(MIDS, x/scale)] exactly:
// positive x: strict <, negative x: <= (tie rounds toward -inf).
__device__ __forceinline__ float quant_one(float v, float inv_scale, float scale) {
  float x = v * inv_scale;          // exact: power-of-2 scale
  float a = fabsf(x);
  int n;
  if (x > 0.f)
    n = (a > 0.25f) + (a > 0.75f) + (a > 1.25f) + (a > 1.75f) +
        (a > 2.5f)  + (a > 3.5f)  + (a > 5.f);
  else
    n = (a >= 0.25f) + (a >= 0.75f) + (a >= 1.25f) + (a >= 1.75f) +
        (a >= 2.5f)  + (a >= 3.5f)  + (a >= 5.f);
  // n -> magnitude {0,.5,1,1.5,2,3,4,6}
  float mag = 0.5f * (float)n + 0.5f * fmaxf((float)(n - 4), 0.f) + (n == 7 ? 1.f : 0.f);
  float q = mag * scale;            // exact
  return x > 0.f ? q : (x < 0.f ? -q : 0.f);
}

// scale = 2^(floor(log2(amax)) - 2) via exponent bits (amax normal, > 0)
__device__ __forceinline__ void make_scale(float amax, float& scale, float& inv) {
  u32 eb = (__float_as_uint(amax) >> 23) & 255u;
  scale = __uint_as_float((eb - 2u) << 23);
  inv   = __uint_as_float((256u - eb) << 23);
}

// values are exactly representable in bf16 -> truncation is exact
__device__ __forceinline__ u16 f2b(float f) {
  return (u16)(__float_as_uint(f) >> 16);
}

// ---------------- routing ----------------
__global__ __launch_bounds__(256)
void route_k(const int* __restrict__ ridx, const float* __restrict__ rw,
             int* __restrict__ tt_e, int* __restrict__ tt_row0, int* __restrict__ tt_rows,
             int* __restrict__ atok, float* __restrict__ awt) {
  __shared__ int cnt[NEXP], cur[NEXP], poff[NEXP];
  int tid = threadIdx.x;
  if (tid < NEXP) { cnt[tid] = 0; cur[tid] = 0; }
  __syncthreads();
  for (int a = tid; a < NASSIGN; a += 256) atomicAdd(&cnt[ridx[a]], 1);
  __syncthreads();
  if (tid == 0) {
    int off = 0, nt = 0;
    for (int e = 0; e < NEXP; ++e) {
      poff[e] = off;
      int cc = cnt[e];
      int ntl = (cc + 127) >> 7;
      for (int i = 0; i < ntl; ++i) {
        int rem = cc - i * 128;
        tt_e[nt] = e; tt_row0[nt] = off + i * 128; tt_rows[nt] = rem < 128 ? rem : 128;
        ++nt;
      }
      off += ntl * 128;
    }
    for (; nt < 64; ++nt) { tt_e[nt] = 0; tt_row0[nt] = 0; tt_rows[nt] = 0; }
  }
  __syncthreads();
  for (int r2 = tid; r2 < MAXPAD; r2 += 256) { atok[r2] = 0; awt[r2] = 0.f; }
  __syncthreads();
  for (int a = tid; a < NASSIGN; a += 256) {
    int e = ridx[a];
    int p = atomicAdd(&cur[e], 1);
    int r2 = poff[e] + p;
    atok[r2] = a >> 2;          // token = a / K
    awt[r2] = rw[a];
  }
}

// ---------------- activation quant: x -> bf16 xq ----------------
__global__ __launch_bounds__(384)
void quant_x_k(const float* __restrict__ x, u16* __restrict__ xq) {
  int t = blockIdx.x;
  int tid = threadIdx.x;
  if (tid >= 360) return;       // 360*8 = 2880
  const float* xp = x + (long)t * HD + tid * 8;
  float4 v0 = *reinterpret_cast<const float4*>(xp);
  float4 v1 = *reinterpret_cast<const float4*>(xp + 4);
  float vv[8] = {v0.x, v0.y, v0.z, v0.w, v1.x, v1.y, v1.z, v1.w};
  float am = 0.f;
#pragma unroll
  for (int j = 0; j < 8; ++j) am = fmaxf(am, fabsf(vv[j]));
  // 4-thread group covers one 32-block (groups aligned within waves)
  am = fmaxf(am, __shfl_xor(am, 1));
  am = fmaxf(am, __shfl_xor(am, 2));
  u16x8 o;
  if (am > 0.f) {
    float scale, inv;
    make_scale(am, scale, inv);
#pragma unroll
    for (int j = 0; j < 8; ++j) o[j] = f2b(quant_one(vv[j], inv, scale));
  } else {
#pragma unroll
    for (int j = 0; j < 8; ++j) o[j] = 0;
  }
  *reinterpret_cast<u16x8*>(xq + (long)t * HD + tid * 8) = o;
}

// ---------------- fused MFMA GEMM ----------------
// BM=128, BK=64, wave tile 64x64 (2x2 frags of 32x32x16 bf16 MFMA).
// IS_GU: A = xq gathered by token; epilogue = bias+act+requant -> gq
// !IS_GU: A = gq rows;            epilogue = bias, *weight, atomicAdd out
template<int BN, int NWN, bool IS_GU>
__global__ __launch_bounds__(128 * NWN)
void moe_gemm(const u16* __restrict__ Asrc,
              const int* __restrict__ codes,
              const int* __restrict__ scales,
              const float* __restrict__ bias,
              const int* __restrict__ tt_e,
              const int* __restrict__ tt_row0,
              const int* __restrict__ tt_rows,
              const int* __restrict__ atok,
              const float* __restrict__ awt,
              u16* __restrict__ gq,
              float* __restrict__ out) {
  constexpr int NT = 128 * NWN;
  constexpr int ND = IS_GU ? GUN : HD;
  constexpr int AI = (1024 + NT - 1) / NT;

  // XCD-chunked bijective swizzle: each XCD gets a contiguous logical range,
  // so the ~4 m-tiles sharing a B panel run adjacently (L2/L3 reuse).
  int nb = gridDim.x * gridDim.y;
  int lin = blockIdx.x + gridDim.x * blockIdx.y;
  int q = nb >> 3, r = nb & 7;
  int xcd = lin & 7, pos = lin >> 3;
  int L = (xcd < r ? xcd * (q + 1) : r * (q + 1) + (xcd - r) * q) + pos;
  int mt = L % (int)gridDim.x;          // m-tile (fast dim -> panel reuse)
  int nt = L / (int)gridDim.x;          // n-tile

  const int rows = tt_rows[mt];
  if (rows <= 0) return;
  const int e = tt_e[mt];
  const int row0 = tt_row0[mt];
  const int tid = threadIdx.x;
  const int lane = tid & 63;
  const int wid = tid >> 6;
  const int wm = wid & 1;
  const int wn = wid >> 1;

  __shared__ __align__(16) u16 Ab[128 * 64];   // [m][k] chunks XOR-swizzled
  __shared__ __align__(16) u16 Bb[BN * 64];    // [n][k] chunks XOR-swizzled

  // ---- A staging precompute (16B chunks; chunk q: m=q>>3, c=q&7) ----
  const u16* aptr[AI];
  int adst[AI];
  bool aval[AI];
#pragma unroll
  for (int i = 0; i < AI; ++i) {
    int qq = tid + i * NT;
    aval[i] = (qq < 1024);
    if (aval[i]) {
      int m = qq >> 3, cc = qq & 7;
      int rowg = row0 + m;
      long rbase = IS_GU ? (long)atok[rowg] * HD : (long)rowg * HD;
      aptr[i] = Asrc + rbase + cc * 8;
      adst[i] = m * 64 + ((cc ^ (m & 7)) << 3);
    } else { aptr[i] = Asrc; adst[i] = 0; }
  }

  // ---- B staging precompute: thread = (f col, 32-k half) ----
  const int fl = tid % BN;
  const int kc = tid / BN;              // 0 or 1
  const int fg = nt * BN + fl;
  const int* csrc = codes + ((long)e * HD + kc * 32) * ND + fg;
  const int* ssrc = scales + ((long)e * SROWS + kc) * ND + fg;
  const int bwbase = fl * 64;

  f32x16 acc[2][2];
#pragma unroll
  for (int a_ = 0; a_ < 2; ++a_)
#pragma unroll
    for (int b_ = 0; b_ < 2; ++b_)
#pragma unroll
      for (int k_ = 0; k_ < 16; ++k_) acc[a_][b_][k_] = 0.f;

  for (int ks = 0; ks < 45; ++ks) {
    // global loads (overlap previous iteration's MFMA)
    int cb[32];
    const int* cp = csrc + (long)ks * 64 * ND;
#pragma unroll
    for (int j = 0; j < 32; ++j) cb[j] = cp[(long)j * ND];
    const int sv = ssrc[(long)ks * 2 * ND];
    const u32 ebase = (u32)(sv + 114) << 7;

    u16x8 av[AI];
#pragma unroll
    for (int i = 0; i < AI; ++i)
      if (aval[i]) av[i] = *reinterpret_cast<const u16x8*>(aptr[i] + ks * 64);

    __syncthreads();   // previous iteration's LDS reads complete

#pragma unroll
    for (int i = 0; i < AI; ++i)
      if (aval[i]) *reinterpret_cast<u16x8*>(&Ab[adst[i]]) = av[i];

    // dequant fp4 -> bf16 bits: ((s+114)<<7) + (lo<<6), lo==1 -> -64, lo==0 -> 0
#pragma unroll
    for (int cc = 0; cc < 4; ++cc) {
      u32 w[4];
#pragma unroll
      for (int p = 0; p < 4; ++p) {
        u32 c0 = (u32)cb[cc * 8 + p * 2];
        u32 c1 = (u32)cb[cc * 8 + p * 2 + 1];
        u32 lo0 = c0 & 7u, lo1 = c1 & 7u;
        u32 b0 = lo0 ? (ebase + (lo0 << 6) - (lo0 == 1u ? 64u : 0u)) : 0u;
        u32 b1 = lo1 ? (ebase + (lo1 << 6) - (lo1 == 1u ? 64u : 0u)) : 0u;
        b0 |= (c0 & 8u) << 12;
        b1 |= (c1 & 8u) << 12;
        w[p] = b0 | (b1 << 16);
      }
      int ci = kc * 4 + cc;
      *reinterpret_cast<uint4*>(&Bb[bwbase + ((ci ^ (fl & 7)) << 3)]) =
          make_uint4(w[0], w[1], w[2], w[3]);
    }

    __syncthreads();

#pragma unroll
    for (int kk = 0; kk < 4; ++kk) {
      const int chunk = kk * 2 + (lane >> 5);
      const int ml = lane & 31;
      short8 af[2], bf[2];
#pragma unroll
      for (int mf = 0; mf < 2; ++mf) {
        int m = wm * 64 + mf * 32 + ml;
        af[mf] = *reinterpret_cast<const short8*>(&Ab[m * 64 + ((chunk ^ (m & 7)) << 3)]);
      }
#pragma unroll
      for (int nf = 0; nf < 2; ++nf) {
        int n = wn * 64 + nf * 32 + ml;
        bf[nf] = *reinterpret_cast<const short8*>(&Bb[n * 64 + ((chunk ^ (n & 7)) << 3)]);
      }
#pragma unroll
      for (int mf = 0; mf < 2; ++mf)
#pragma unroll
        for (int nf = 0; nf < 2; ++nf)
          acc[mf][nf] = __builtin_amdgcn_mfma_f32_32x32x16_bf16(af[mf], bf[nf], acc[mf][nf], 0, 0, 0);
    }
  }

  // ---- epilogues ----
  const int ml = lane & 31;
  const int hlf = lane >> 5;
  if (IS_GU) {
#pragma unroll
    for (int mf = 0; mf < 2; ++mf) {
      float gated[2][16];
      bool evenl = ((lane & 1) == 0);
#pragma unroll
      for (int nf = 0; nf < 2; ++nf) {
        int flc = wn * 64 + nf * 32 + ml;
        int fgc = nt * BN + flc;
        float bown = bias[e * GUN + fgc];
#pragma unroll
        for (int rr = 0; rr < 16; ++rr) {
          float z = acc[mf][nf][rr] + bown;
          float zp = __shfl_xor(z, 1);           // partner col (gate/up pair)
          float g = evenl ? z : zp;
          float u = evenl ? zp : z;
          g = fminf(g, 7.f);
          u = fminf(fmaxf(u, -7.f), 7.f);
          float sg = 1.f / (1.f + expf(-1.702f * g));
          gated[nf][rr] = (u + 1.f) * (g * sg);
        }
      }
#pragma unroll
      for (int rr = 0; rr < 16; ++rr) {
        float am = fmaxf(fabsf(gated[0][rr]), fabsf(gated[1][rr]));
        am = fmaxf(am, __shfl_xor(am, 2));
        am = fmaxf(am, __shfl_xor(am, 4));
        am = fmaxf(am, __shfl_xor(am, 8));
        am = fmaxf(am, __shfl_xor(am, 16));
        int mrow = (rr & 3) + 8 * (rr >> 2) + 4 * hlf;
        int rloc = wm * 64 + mf * 32 + mrow;
        u16 o0 = 0, o1 = 0;
        if (am > 0.f) {
          float scale, inv;
          make_scale(am, scale, inv);
          o0 = f2b(quant_one(gated[0][rr], inv, scale));
          o1 = f2b(quant_one(gated[1][rr], inv, scale));
        }
        if (rloc < rows && (lane & 1) == 0) {
          long rg = row0 + rloc;
          int ig = nt * 64 + wn * 32 + (ml >> 1);
          gq[rg * HD + ig] = o0;
          gq[rg * HD + ig + 16] = o1;
        }
      }
    }
  } else {
#pragma unroll
    for (int mf = 0; mf < 2; ++mf) {
#pragma unroll
      for (int rr = 0; rr < 16; ++rr) {
        int mrow = (rr & 3) + 8 * (rr >> 2) + 4 * hlf;
        int rloc = wm * 64 + mf * 32 + mrow;
        if (rloc >= rows) continue;
        int rg = row0 + rloc;
        float wgt = awt[rg];
        long tok = atok[rg];
#pragma unroll
        for (int nf = 0; nf < 2; ++nf) {
          int hg = nt * BN + wn * 64 + nf * 32 + ml;
          float v = (acc[mf][nf][rr] + bias[e * HD + hg]) * wgt;
          atomicAdd(&out[tok * HD + hg], v);
        }
      }
    }
  }
}

// ---------------- launcher ----------------
extern "C" void kernel_launch(void* const* d_in, const int* in_sizes, int n_in,
                              void* d_out, int out_size, void* d_ws, size_t ws_size,
                              hipStream_t stream) {
  (void)in_sizes; (void)n_in; (void)ws_size;
  const float* x   = (const float*)d_in[0];
  const int* ridx  = (const int*)d_in[1];
  const float* rw  = (const float*)d_in[2];
  const int* guc   = (const int*)d_in[3];
  const int* gus   = (const int*)d_in[4];
  const float* gub = (const float*)d_in[5];
  const int* dnc   = (const int*)d_in[6];
  const int* dns   = (const int*)d_in[7];
  const float* dnb = (const float*)d_in[8];
  float* out = (float*)d_out;
  char* ws = (char*)d_ws;

  // ws layout (~35.5 MB total)
  int* tt_e    = (int*)(ws);
  int* tt_row0 = (int*)(ws + 1024);
  int* tt_rows = (int*)(ws + 2048);
  int* atok    = (int*)(ws + 4096);
  float* awt   = (float*)(ws + 4096 + MAXPAD * 4);
  u16* xq      = (u16*)(ws + 65536);
  u16* gq      = (u16*)(ws + 65536 + (size_t)NTOK * HD * 2);

  hipMemsetAsync(d_out, 0, (size_t)out_size * sizeof(float), stream);
  route_k<<<1, 256, 0, stream>>>(ridx, rw, tt_e, tt_row0, tt_rows, atok, awt);
  quant_x_k<<<NTOK, 384, 0, stream>>>(x, xq);
  moe_gemm<128, 2, true><<<dim3(MAXTILES, 45), 256, 0, stream>>>(
      xq, guc, gus, gub, tt_e, tt_row0, tt_rows, atok, awt, gq, nullptr);
  moe_gemm<192, 3, false><<<dim3(MAXTILES, 15), 384, 0, stream>>>(
      gq, dnc, dns, dnb, tt_e, tt_row0, tt_rows, atok, awt, nullptr, out);
}

// Round 2
// 902.014 us; speedup vs baseline: 1.1574x; 1.1574x over previous
//
#include <hip/hip_runtime.h>
#include <hip/hip_bf16.h>

typedef unsigned short u16;
typedef unsigned int u32;
typedef short short8 __attribute__((ext_vector_type(8)));
typedef u16 u16x8 __attribute__((ext_vector_type(8)));
typedef float f32x16 __attribute__((ext_vector_type(16)));

#define HD 2880          // H == I == 2880
#define GUN 5760         // 2*I
#define NEXP 8
#define NTOK 1024
#define NASSIGN 4096     // T*K
#define MAXPAD 5120      // 4096 + 8*127 rounded up
#define MAXTILES 40
#define SROWS 90         // 2880/32

// ---------------- global -> LDS direct staging (16B per lane) ----------------
__device__ __forceinline__ void gll16(const u16* g, u16* l) {
  __builtin_amdgcn_global_load_lds(
      (const __attribute__((address_space(1))) u32*)(const void*)g,
      (__attribute__((address_space(3))) u32*)(void*)l, 16, 0, 0);
}

// ---------------- exact mxfp4 quant helpers ----------------
__device__ __forceinline__ float quant_one(float v, float inv_scale, float scale) {
  float x = v * inv_scale;
  float a = fabsf(x);
  int n;
  if (x > 0.f)
    n = (a > 0.25f) + (a > 0.75f) + (a > 1.25f) + (a > 1.75f) +
        (a > 2.5f)  + (a > 3.5f)  + (a > 5.f);
  else
    n = (a >= 0.25f) + (a >= 0.75f) + (a >= 1.25f) + (a >= 1.75f) +
        (a >= 2.5f)  + (a >= 3.5f)  + (a >= 5.f);
  float mag = 0.5f * (float)n + 0.5f * fmaxf((float)(n - 4), 0.f) + (n == 7 ? 1.f : 0.f);
  float q = mag * scale;
  return x > 0.f ? q : (x < 0.f ? -q : 0.f);
}

__device__ __forceinline__ void make_scale(float amax, float& scale, float& inv) {
  u32 eb = (__float_as_uint(amax) >> 23) & 255u;
  scale = __uint_as_float((eb - 2u) << 23);
  inv   = __uint_as_float((256u - eb) << 23);
}

__device__ __forceinline__ u16 f2b(float f) {
  return (u16)(__float_as_uint(f) >> 16);
}

// ---------------- routing ----------------
__global__ __launch_bounds__(256)
void route_k(const int* __restrict__ ridx, const float* __restrict__ rw,
             int* __restrict__ tt_e, int* __restrict__ tt_row0, int* __restrict__ tt_rows,
             int* __restrict__ atok, float* __restrict__ awt) {
  __shared__ int cnt[NEXP], cur[NEXP], poff[NEXP];
  int tid = threadIdx.x;
  if (tid < NEXP) { cnt[tid] = 0; cur[tid] = 0; }
  __syncthreads();
  for (int a = tid; a < NASSIGN; a += 256) atomicAdd(&cnt[ridx[a]], 1);
  __syncthreads();
  if (tid == 0) {
    int off = 0, nt = 0;
    for (int e = 0; e < NEXP; ++e) {
      poff[e] = off;
      int cc = cnt[e];
      int ntl = (cc + 127) >> 7;
      for (int i = 0; i < ntl; ++i) {
        int rem = cc - i * 128;
        tt_e[nt] = e; tt_row0[nt] = off + i * 128; tt_rows[nt] = rem < 128 ? rem : 128;
        ++nt;
      }
      off += ntl * 128;
    }
    for (; nt < 64; ++nt) { tt_e[nt] = 0; tt_row0[nt] = 0; tt_rows[nt] = 0; }
  }
  __syncthreads();
  for (int r2 = tid; r2 < MAXPAD; r2 += 256) { atok[r2] = 0; awt[r2] = 0.f; }
  __syncthreads();
  for (int a = tid; a < NASSIGN; a += 256) {
    int e = ridx[a];
    int p = atomicAdd(&cur[e], 1);
    int r2 = poff[e] + p;
    atok[r2] = a >> 2;
    awt[r2] = rw[a];
  }
}

// ---------------- activation quant: x -> bf16 xq ----------------
__global__ __launch_bounds__(384)
void quant_x_k(const float* __restrict__ x, u16* __restrict__ xq) {
  int t = blockIdx.x;
  int tid = threadIdx.x;
  if (tid >= 360) return;       // 360*8 = 2880
  const float* xp = x + (long)t * HD + tid * 8;
  float4 v0 = *reinterpret_cast<const float4*>(xp);
  float4 v1 = *reinterpret_cast<const float4*>(xp + 4);
  float vv[8] = {v0.x, v0.y, v0.z, v0.w, v1.x, v1.y, v1.z, v1.w};
  float am = 0.f;
#pragma unroll
  for (int j = 0; j < 8; ++j) am = fmaxf(am, fabsf(vv[j]));
  am = fmaxf(am, __shfl_xor(am, 1));
  am = fmaxf(am, __shfl_xor(am, 2));
  u16x8 o;
  if (am > 0.f) {
    float scale, inv;
    make_scale(am, scale, inv);
#pragma unroll
    for (int j = 0; j < 8; ++j) o[j] = f2b(quant_one(vv[j], inv, scale));
  } else {
#pragma unroll
    for (int j = 0; j < 8; ++j) o[j] = 0;
  }
  *reinterpret_cast<u16x8*>(xq + (long)t * HD + tid * 8) = o;
}

// ---------------- weight dequant-transpose: codes[e][h][f] -> wT[e][f][h] bf16 ----
// grid: (f_tile = ND/320, h_block = 90, e = 8); one thread = one f, 32 h values.
__global__ __launch_bounds__(320)
void repack_k(const int* __restrict__ codes, const int* __restrict__ scales,
              u16* __restrict__ wT, int ND) {
  const int f = blockIdx.x * 320 + threadIdx.x;
  const int hb = blockIdx.y;
  const int e = blockIdx.z;
  const long cbase = ((long)e * HD + hb * 32) * ND + f;
  const int s = scales[((long)e * SROWS + hb) * ND + f];
  const u32 ebase = (u32)(s + 114) << 7;
  u16x8 vv[4];
#pragma unroll
  for (int h = 0; h < 32; ++h) {
    u32 c = (u32)codes[cbase + (long)h * ND];
    u32 lo = c & 7u;
    u32 b = lo ? (ebase + (lo << 6) - (lo == 1u ? 64u : 0u)) : 0u;
    b |= (c & 8u) << 12;
    vv[h >> 3][h & 7] = (u16)b;
  }
  u16* dst = wT + ((long)e * ND + f) * HD + hb * 32;
#pragma unroll
  for (int i = 0; i < 4; ++i)
    *reinterpret_cast<u16x8*>(dst + i * 8) = vv[i];
}

// ---------------- bf16 MFMA GEMM (both operands k-contiguous) ----------------
// BM=128, BK=64, wave tile 64x64 (2x2 frags of 32x32x16 bf16 MFMA).
// IS_GU: A = xq gathered by token; epilogue = bias+act+requant -> gq
// !IS_GU: A = gq rows;            epilogue = bias, *weight, atomicAdd out
template<int BN, int NWT, bool IS_GU>
__global__ __launch_bounds__(64 * NWT)
void moe_gemm(const u16* __restrict__ Asrc,
              const u16* __restrict__ wT,
              const float* __restrict__ bias,
              const int* __restrict__ tt_e,
              const int* __restrict__ tt_row0,
              const int* __restrict__ tt_rows,
              const int* __restrict__ atok,
              const float* __restrict__ awt,
              u16* __restrict__ gq,
              float* __restrict__ out) {
  constexpr int NT = 64 * NWT;
  constexpr int ND = IS_GU ? GUN : HD;
  constexpr int AI = (1024 + NT - 1) / NT;   // A 16B-chunks per thread
  constexpr int BI = BN * 8 / NT;            // B 16B-chunks per thread

  // XCD-chunked bijective swizzle, m-tile fastest (B-panel L2 reuse)
  int nb = gridDim.x * gridDim.y;
  int lin = blockIdx.x + gridDim.x * blockIdx.y;
  int q_ = nb >> 3, r_ = nb & 7;
  int xcd = lin & 7, pos = lin >> 3;
  int L = (xcd < r_ ? xcd * (q_ + 1) : r_ * (q_ + 1) + (xcd - r_) * q_) + pos;
  int mt = L % (int)gridDim.x;
  int nt = L / (int)gridDim.x;

  const int rows = tt_rows[mt];
  if (rows <= 0) return;
  const int e = tt_e[mt];
  const int row0 = tt_row0[mt];
  const int tid = threadIdx.x;
  const int lane = tid & 63;
  const int wid = tid >> 6;
  const int wm = wid & 1;
  const int wn = wid >> 1;

  __shared__ __align__(16) u16 Ab[128 * 64];   // [m][k], chunk c at ((c^(m&7))<<3)
  __shared__ __align__(16) u16 Bb[BN * 64];    // [n][k], same swizzle

  // staging source pointers; LDS dest is LINEAR (chunk q at byte q*16) so the
  // XOR swizzle is applied on the GLOBAL source address (rule: both-sides swizzle)
  const u16* asrc[AI];
  bool aval[AI];
#pragma unroll
  for (int i = 0; i < AI; ++i) {
    int q = tid + i * NT;
    aval[i] = (q < 1024);
    if (aval[i]) {
      int m = q >> 3, cl = q & 7, cg = cl ^ (m & 7);
      long rowbase = IS_GU ? (long)atok[row0 + m] * HD : (long)(row0 + m) * HD;
      asrc[i] = Asrc + rowbase + cg * 8;
    } else asrc[i] = Asrc;
  }
  const u16* bsrc[BI];
#pragma unroll
  for (int i = 0; i < BI; ++i) {
    int q = tid + i * NT;
    int n = q >> 3, cl = q & 7, cg = cl ^ (n & 7);
    bsrc[i] = wT + ((long)e * ND + (long)nt * BN + n) * HD + cg * 8;
  }

  f32x16 acc[2][2];
#pragma unroll
  for (int a_ = 0; a_ < 2; ++a_)
#pragma unroll
    for (int b_ = 0; b_ < 2; ++b_)
#pragma unroll
      for (int k_ = 0; k_ < 16; ++k_) acc[a_][b_][k_] = 0.f;

  for (int ks = 0; ks < 45; ++ks) {
    const int ko = ks * 64;
#pragma unroll
    for (int i = 0; i < AI; ++i)
      if (aval[i]) gll16(asrc[i] + ko, Ab + (tid + i * NT) * 8);
#pragma unroll
    for (int i = 0; i < BI; ++i)
      gll16(bsrc[i] + ko, Bb + (tid + i * NT) * 8);

    __syncthreads();   // vmcnt(0) drain: staged tile visible

    const int ml = lane & 31;
#pragma unroll
    for (int kk = 0; kk < 4; ++kk) {
      const int chunk = kk * 2 + (lane >> 5);
      short8 af[2], bf[2];
#pragma unroll
      for (int mf = 0; mf < 2; ++mf) {
        int m = wm * 64 + mf * 32 + ml;
        af[mf] = *reinterpret_cast<const short8*>(&Ab[m * 64 + ((chunk ^ (m & 7)) << 3)]);
      }
#pragma unroll
      for (int nf = 0; nf < 2; ++nf) {
        int n = wn * 64 + nf * 32 + ml;
        bf[nf] = *reinterpret_cast<const short8*>(&Bb[n * 64 + ((chunk ^ (n & 7)) << 3)]);
      }
#pragma unroll
      for (int mf = 0; mf < 2; ++mf)
#pragma unroll
        for (int nf = 0; nf < 2; ++nf)
          acc[mf][nf] = __builtin_amdgcn_mfma_f32_32x32x16_bf16(af[mf], bf[nf], acc[mf][nf], 0, 0, 0);
    }

    __syncthreads();   // all reads done before next stage overwrites
  }

  // ---- epilogues (verified in round 1) ----
  const int ml = lane & 31;
  const int hlf = lane >> 5;
  if (IS_GU) {
#pragma unroll
    for (int mf = 0; mf < 2; ++mf) {
      float gated[2][16];
      bool evenl = ((lane & 1) == 0);
#pragma unroll
      for (int nf = 0; nf < 2; ++nf) {
        int flc = wn * 64 + nf * 32 + ml;
        int fgc = nt * BN + flc;
        float bown = bias[e * GUN + fgc];
#pragma unroll
        for (int rr = 0; rr < 16; ++rr) {
          float z = acc[mf][nf][rr] + bown;
          float zp = __shfl_xor(z, 1);
          float g = evenl ? z : zp;
          float u = evenl ? zp : z;
          g = fminf(g, 7.f);
          u = fminf(fmaxf(u, -7.f), 7.f);
          float sg = 1.f / (1.f + expf(-1.702f * g));
          gated[nf][rr] = (u + 1.f) * (g * sg);
        }
      }
#pragma unroll
      for (int rr = 0; rr < 16; ++rr) {
        float am = fmaxf(fabsf(gated[0][rr]), fabsf(gated[1][rr]));
        am = fmaxf(am, __shfl_xor(am, 2));
        am = fmaxf(am, __shfl_xor(am, 4));
        am = fmaxf(am, __shfl_xor(am, 8));
        am = fmaxf(am, __shfl_xor(am, 16));
        int mrow = (rr & 3) + 8 * (rr >> 2) + 4 * hlf;
        int rloc = wm * 64 + mf * 32 + mrow;
        u16 o0 = 0, o1 = 0;
        if (am > 0.f) {
          float scale, inv;
          make_scale(am, scale, inv);
          o0 = f2b(quant_one(gated[0][rr], inv, scale));
          o1 = f2b(quant_one(gated[1][rr], inv, scale));
        }
        if (rloc < rows && (lane & 1) == 0) {
          long rg = row0 + rloc;
          int ig = nt * 64 + wn * 32 + (ml >> 1);
          gq[rg * HD + ig] = o0;
          gq[rg * HD + ig + 16] = o1;
        }
      }
    }
  } else {
#pragma unroll
    for (int mf = 0; mf < 2; ++mf) {
#pragma unroll
      for (int rr = 0; rr < 16; ++rr) {
        int mrow = (rr & 3) + 8 * (rr >> 2) + 4 * hlf;
        int rloc = wm * 64 + mf * 32 + mrow;
        if (rloc >= rows) continue;
        int rg = row0 + rloc;
        float wgt = awt[rg];
        long tok = atok[rg];
#pragma unroll
        for (int nf = 0; nf < 2; ++nf) {
          int hg = nt * BN + wn * 64 + nf * 32 + ml;
          float v = (acc[mf][nf][rr] + bias[e * HD + hg]) * wgt;
          atomicAdd(&out[tok * HD + hg], v);
        }
      }
    }
  }
}

// ---------------- launcher ----------------
extern "C" void kernel_launch(void* const* d_in, const int* in_sizes, int n_in,
                              void* d_out, int out_size, void* d_ws, size_t ws_size,
                              hipStream_t stream) {
  (void)in_sizes; (void)n_in; (void)ws_size;
  const float* x   = (const float*)d_in[0];
  const int* ridx  = (const int*)d_in[1];
  const float* rw  = (const float*)d_in[2];
  const int* guc   = (const int*)d_in[3];
  const int* gus   = (const int*)d_in[4];
  const float* gub = (const float*)d_in[5];
  const int* dnc   = (const int*)d_in[6];
  const int* dns   = (const int*)d_in[7];
  const float* dnb = (const float*)d_in[8];
  float* out = (float*)d_out;
  char* ws = (char*)d_ws;

  // ws layout: routing (64KB) | xq (5.9MB) | gq (29.5MB) | wT (265.4MB) ~= 288MB
  int* tt_e    = (int*)(ws);
  int* tt_row0 = (int*)(ws + 1024);
  int* tt_rows = (int*)(ws + 2048);
  int* atok    = (int*)(ws + 4096);
  float* awt   = (float*)(ws + 4096 + MAXPAD * 4);
  u16* xq      = (u16*)(ws + 65536);
  u16* gq      = (u16*)(ws + 65536 + (size_t)NTOK * HD * 2);
  u16* wT      = (u16*)(ws + 65536 + (size_t)NTOK * HD * 2 + (size_t)MAXPAD * HD * 2);

  hipMemsetAsync(d_out, 0, (size_t)out_size * sizeof(float), stream);
  route_k<<<1, 256, 0, stream>>>(ridx, rw, tt_e, tt_row0, tt_rows, atok, awt);
  quant_x_k<<<NTOK, 384, 0, stream>>>(x, xq);
  repack_k<<<dim3(GUN / 320, SROWS, NEXP), 320, 0, stream>>>(guc, gus, wT, GUN);
  moe_gemm<128, 4, true><<<dim3(MAXTILES, 45), 256, 0, stream>>>(
      xq, wT, gub, tt_e, tt_row0, tt_rows, atok, awt, gq, nullptr);
  repack_k<<<dim3(HD / 320, SROWS, NEXP), 320, 0, stream>>>(dnc, dns, wT, HD);
  moe_gemm<192, 6, false><<<dim3(MAXTILES, 15), 384, 0, stream>>>(
      gq, wT, dnb, tt_e, tt_row0, tt_rows, atok, awt, nullptr, out);
}